// Round 17
// baseline (65.594 us; speedup 1.0000x reference)
//
#include <hip/hip_runtime.h>
#include <stdint.h>

// SCLinear: out = sc_mat_mac_p(x, W, b, lut, 32)  (forward value of
// lin + stop_grad(p - lin) is exactly p).
// lut[i][j] == floor(i*j/32)  =>  sgn*lut[|a|,|b|] == trunc-toward-zero(a*b/32).
// Exact small-integer arithmetic; no lut memory needed.
//
// R30: R29 + W-LOAD ISSUE-EARLY / TILE PIPELINE.
// R26==R27 (occupancy-insensitive), R28 (-4.4us, VALU cut), R29 (-2.4us,
// DS cut) => kernel tracks per-CU totals; remaining ~13.5us has ~2us
// VALU + ~1.7us L1 steady-state, rest is critical-path serialization.
// This round attacks the startup chain: W loads were gated behind the
// x-quantize barrier although they don't depend on a_sh.
//  1. c=0 W tile (4x float4) prefetched BEFORE __syncthreads -- all 16
//     waves issue loads while waves 0,1 quantize x. (W read-only,
//     disjoint from LDS; barrier only orders a_sh.)
//  2. Rolling prefetch: tile c+1 issued before computing tile c
//     (register double-buffer, fully unrolled).
//  3. b[] load hoisted above the MAC.
// Everything else verbatim R29: 4-rows-in-flight packed butterfly,
// float-trick exact MAC, coalesced loads (W once per block),
// communication-free dmax, publish-early/poll-late amax (sc0sc1),
// speculative (5,5) + exact block-uniform fixup.
// 256 blocks x 1024 threads. wsp[bx] = block bx's x-rowpair absmax
// (bit31==0 ready flag; harness poison 0xAA.. has bit31=1).

#define MROWS 512
#define KDIM  256
#define OCOLS 256
#define NTHR  1024
#define RPB   2
#define NBLK  (MROWS / RPB)     // 256
#define NWAVE (NTHR / 64)       // 16
#define ROWS_PER_WAVE (OCOLS / NWAVE)   // 16
#define E2_GUESS 5
#define E1_GUESS 5

typedef unsigned int u32x4 __attribute__((ext_vector_type(4)));

__device__ __forceinline__ void store_uc(unsigned int* p, unsigned int v) {
    asm volatile("global_store_dword %0, %1, off sc0 sc1"
                 :: "v"((unsigned long long)(uintptr_t)p), "v"(v) : "memory");
}
__device__ __forceinline__ u32x4 load_uc4(const unsigned int* p) {
    u32x4 v;
    asm volatile("global_load_dwordx4 %0, %1, off sc0 sc1\n\t"
                 "s_waitcnt vmcnt(0)"
                 : "=v"(v) : "v"((unsigned long long)(uintptr_t)p) : "memory");
    return v;
}
__device__ __forceinline__ unsigned int pk_add_i16(unsigned int a, unsigned int b) {
    unsigned int d;
    asm("v_pk_add_i16 %0, %1, %2" : "=v"(d) : "v"(a), "v"(b));
    return d;
}

__device__ __forceinline__ void get_scales(float amax, float dmax, int& e2, int& e1) {
    if (amax == 0.0f) amax = 1.0f;
    if (dmax == 0.0f) dmax = 1.0f;
    float q2 = 32.0f / amax;
    float q1 = 32.0f / dmax;
    int f2 = (q2 >= 1073741824.0f) ? 0x40000000 : (int)floorf(q2);
    int f1 = (q1 >= 1073741824.0f) ? 0x40000000 : (int)floorf(q1);
    if (f2 < 1) f2 = 1;
    if (f1 < 1) f1 = 1;
    e2 = 31 - __clz(f2);
    e1 = 31 - __clz(f1);
}

__device__ __forceinline__ float max4(float4 v) {
    return fmaxf(fmaxf(fabsf(v.x), fabsf(v.y)), fmaxf(fabsf(v.z), fabsf(v.w)));
}

// Load one 4-row tile: group g's row for iteration index cc, lane's 16
// k-elements as 4x float4 (coalesced: 4 rows x 256B per instruction).
__device__ __forceinline__ void load_tile(const float4* __restrict__ wq,
                                          int obase, int cc, int t, int g,
                                          float4 wv[4]) {
    const int o = obase + 4 * cc + g;
    #pragma unroll
    for (int c2 = 0; c2 < 4; ++c2)
        wv[c2] = wq[(size_t)o * (KDIM / 4) + t + 16 * c2];
}

// Wave-cooperative MAC, 4 rows in flight, software-pipelined: tile c+1
// is issued before tile c is computed. cur[] holds the pre-loaded c=0
// tile. Returns packed {s1:hi,s0:lo} for this lane's target row
// obase+(lane&15). Folds max|W| over everything loaded into wmax.
__device__ __forceinline__ unsigned int wave_mac(const float4* __restrict__ wq,
                                                 int obase, int lane, int rot,
                                                 u32x4 xp0, u32x4 xp1,
                                                 float sn1f, float& wmax,
                                                 float4 cur[4]) {
    // av/32 floats for the lane's 16 k-elements x 2 x-rows (dyadic-exact).
    float a0f[4][4], a1f[4][4];
    unsigned int xw0[4] = {xp0.x, xp0.y, xp0.z, xp0.w};
    unsigned int xw1[4] = {xp1.x, xp1.y, xp1.z, xp1.w};
    #pragma unroll
    for (int c2 = 0; c2 < 4; ++c2) {
        #pragma unroll
        for (int j = 0; j < 4; ++j) {
            a0f[c2][j] = (float)(((int)(xw0[c2] << (24 - 8 * j))) >> 24) * 0.03125f;
            a1f[c2][j] = (float)(((int)(xw1[c2] << (24 - 8 * j))) >> 24) * 0.03125f;
        }
    }
    const int t = lane & 15;
    const int g = lane >> 4;
    unsigned int res0 = 0, res1 = 0, res2 = 0, res3 = 0;
    float4 nxt[4];
    #pragma unroll
    for (int c = 0; c < 4; ++c) {
        if (c < 3)                                     // prefetch tile c+1
            load_tile(wq, obase, (c + 1 + rot) & 3, t, g, nxt);
        int s0 = 0, s1 = 0;
        #pragma unroll
        for (int c2 = 0; c2 < 4; ++c2) {
            wmax = fmaxf(wmax, max4(cur[c2]));
            float wf[4] = {cur[c2].x, cur[c2].y, cur[c2].z, cur[c2].w};
            #pragma unroll
            for (int j = 0; j < 4; ++j) {
                float bvf = truncf(wf[j] * sn1f);      // == (float)bv, exact
                s0 += (int)(a0f[c2][j] * bvf);         // == trunc(av0*bv/32)
                s1 += (int)(a1f[c2][j] * bvf);
            }
        }
        // |per-lane partial| <= 512, |row sum| <= 8192 -> int16-safe.
        unsigned int s = (unsigned int)(s0 & 0xFFFF) | ((unsigned int)s1 << 16);
        #pragma unroll
        for (int sft = 8; sft >= 1; sft >>= 1)         // within-16 butterfly
            s = pk_add_i16(s, (unsigned int)__shfl_xor((int)s, sft, 64));
        if (c == 0) res0 = s; else if (c == 1) res1 = s;
        else if (c == 2) res2 = s; else res3 = s;
        if (c < 3) {
            #pragma unroll
            for (int c2 = 0; c2 < 4; ++c2) cur[c2] = nxt[c2];
        }
    }
    // Gather: lane's target row r=lane&15 was produced by group r&3 in the
    // iteration c with (c+rot)&3 == r>>2.
    const int r   = lane & 15;
    const int src = ((r & 3) << 4) + t;                // any lane of group r&3
    unsigned int v0 = (unsigned int)__shfl((int)res0, src, 64);
    unsigned int v1 = (unsigned int)__shfl((int)res1, src, 64);
    unsigned int v2 = (unsigned int)__shfl((int)res2, src, 64);
    unsigned int v3 = (unsigned int)__shfl((int)res3, src, 64);
    const int csel = ((r >> 2) - rot) & 3;
    return (csel == 0) ? v0 : (csel == 1) ? v1 : (csel == 2) ? v2 : v3;
}

__global__ __launch_bounds__(NTHR)
void k_one(unsigned int* __restrict__ wsp, const float* __restrict__ x,
           const float* __restrict__ W, const float* __restrict__ b,
           float* __restrict__ out) {
    __shared__ unsigned int a_sh[RPB][KDIM / 4];
    __shared__ float sm[2];          // x-rowpair partials from waves 0,1
    __shared__ float smd[NWAVE];     // dmax partials
    __shared__ int s_e[2];

    const int tid  = threadIdx.x;
    const int lane = tid & 63;
    const int w    = tid >> 6;
    const int bx   = blockIdx.x;
    const int m0   = bx * RPB;
    const int rot  = bx & 3;
    const int t    = lane & 15;
    const int g    = lane >> 4;
    const int obase = w * ROWS_PER_WAVE;

    const float4* xf = (const float4*)x;
    const float4* wq = (const float4*)W;

    // ---- issue the block's x loads (waves 0,1), then EVERY wave's c=0 W
    //      tile, then b -- all before any barrier ----
    const bool qa = tid < RPB * (KDIM / 4);  // 128 threads (waves 0,1)
    float4 xv;
    if (qa)
        xv = xf[(size_t)(m0 + (tid >> 6)) * (KDIM / 4) + (tid & 63)];
    float4 tile0[4];
    load_tile(wq, obase, rot, t, g, tile0);  // c=0 tile, issued pre-barrier
    const float bo = b[obase + t];

    // ---- speculative quantize of the block's 2 x-rows + rowpair amax ----
    float rm = 0.0f;
    if (qa) {
        rm = max4(xv);
        const float g2 = (float)(1 << E2_GUESS);
        int a0 = (int)(xv.x * g2) & 0xFF;
        int a1 = (int)(xv.y * g2) & 0xFF;
        int a2 = (int)(xv.z * g2) & 0xFF;
        int a3 = (int)(xv.w * g2) & 0xFF;
        a_sh[tid >> 6][tid & 63] =
            (unsigned int)(a0 | (a1 << 8) | (a2 << 16) | (a3 << 24));
    }
    if (w < 2) {
        #pragma unroll
        for (int s = 32; s >= 1; s >>= 1)
            rm = fmaxf(rm, __shfl_xor(rm, s, 64));
        if (lane == 0) sm[w] = rm;
    }
    __syncthreads();
    // ---- PUBLISH EARLY: one dword per block ----
    if (tid == 0)
        store_uc(&wsp[bx], __float_as_uint(fmaxf(sm[0], sm[1])));

    // ---- x-slice preload (8 ds_reads) + pipelined 4-row-group MAC ----
    u32x4 xp0, xp1;
    xp0.x = a_sh[0][t];      xp0.y = a_sh[0][t + 16];
    xp0.z = a_sh[0][t + 32]; xp0.w = a_sh[0][t + 48];
    xp1.x = a_sh[1][t];      xp1.y = a_sh[1][t + 16];
    xp1.z = a_sh[1][t + 32]; xp1.w = a_sh[1][t + 48];
    float wm = 0.0f;
    unsigned int res = wave_mac(wq, obase, lane, rot, xp0, xp1,
                                (float)(1 << E1_GUESS), wm, tile0);

    wm = fmaxf(wm, fabsf(bo));               // waves jointly cover all of b
    #pragma unroll
    for (int s = 32; s >= 1; s >>= 1)
        wm = fmaxf(wm, __shfl_xor(wm, s, 64));
    if (lane == 0) smd[w] = wm;
    __syncthreads();

    // ---- CONSUME LATE: poll the 256 block maxes (one dwordx4/lane) ----
    if (w == 0) {
        u32x4 u;
        bool ok;
        do {
            u = load_uc4(&wsp[4 * lane]);    // lanes 0..63 cover 256 dwords
            ok = __all(((u.x | u.y | u.z | u.w) & 0x80000000u) == 0u);
            if (!ok) __builtin_amdgcn_s_sleep(1);
        } while (!ok);
        float va = fmaxf(fmaxf(__uint_as_float(u.x), __uint_as_float(u.y)),
                         fmaxf(__uint_as_float(u.z), __uint_as_float(u.w)));
        #pragma unroll
        for (int s = 32; s >= 1; s >>= 1)
            va = fmaxf(va, __shfl_xor(va, s, 64));
        if (lane == 0) {
            float vd = smd[0];
            #pragma unroll
            for (int i = 1; i < NWAVE; ++i) vd = fmaxf(vd, smd[i]);
            int e2, e1;
            get_scales(va, vd, e2, e1);      // vd is EXACT local dmax(W,b)
            s_e[0] = e2; s_e[1] = e1;
        }
    }
    __syncthreads();

    const int e2 = s_e[0];
    const int e1 = s_e[1];

    // ---- block-uniform fixup if the guess was wrong (never for bench
    //      data; exact for arbitrary inputs) ----
    if ((e2 != E2_GUESS) | (e1 != E1_GUESS)) {
        if (qa) {
            float4 yv = xf[(size_t)(m0 + (tid >> 6)) * (KDIM / 4) + (tid & 63)];
            const float t2 = (float)(1 << e2);
            int a0 = (int)(yv.x * t2) & 0xFF;
            int a1 = (int)(yv.y * t2) & 0xFF;
            int a2 = (int)(yv.z * t2) & 0xFF;
            int a3 = (int)(yv.w * t2) & 0xFF;
            a_sh[tid >> 6][tid & 63] =
                (unsigned int)(a0 | (a1 << 8) | (a2 << 16) | (a3 << 24));
        }
        __syncthreads();
        u32x4 yp0, yp1;
        yp0.x = a_sh[0][t];      yp0.y = a_sh[0][t + 16];
        yp0.z = a_sh[0][t + 32]; yp0.w = a_sh[0][t + 48];
        yp1.x = a_sh[1][t];      yp1.y = a_sh[1][t + 16];
        yp1.z = a_sh[1][t + 32]; yp1.w = a_sh[1][t + 48];
        float4 tileF[4];
        load_tile(wq, obase, rot, t, g, tileF);
        float dummy = 0.0f;
        res = wave_mac(wq, obase, lane, rot, yp0, yp1,
                       (float)(1 << e1), dummy, tileF);
    }

    // ---- epilogue: lanes 0..15 store both x-rows for their column ----
    if (lane < 16) {
        const int s0 = (int)(short)(res & 0xFFFF);
        const int s1 = (int)res >> 16;
        const float sn1f = (float)(1 << e1);
        const int cc = (int)(bo * sn1f);
        const int mask = (1 << e2) - 1;
        const int d0 = ((s0 + ((s0 >> 31) & mask)) >> e2) + cc;
        const int d1 = ((s1 + ((s1 >> 31) & mask)) >> e2) + cc;
        const float inv = 1.0f / sn1f;
        out[(size_t)m0 * OCOLS + obase + lane]       = (float)d0 * inv;
        out[(size_t)(m0 + 1) * OCOLS + obase + lane] = (float)d1 * inv;
    }
}

extern "C" void kernel_launch(void* const* d_in, const int* in_sizes, int n_in,
                              void* d_out, int out_size, void* d_ws, size_t ws_size,
                              hipStream_t stream) {
    const float* x = (const float*)d_in[0];
    const float* W = (const float*)d_in[1];
    const float* b = (const float*)d_in[2];
    // d_in[3] (lut) unused: lut[i][j] == floor(i*j/32), computed in-ALU.
    float* out = (float*)d_out;
    unsigned int* wsp = (unsigned int*)d_ws;   // 1 KB: per-block x-rowpair maxes

    k_one<<<NBLK, NTHR, 0, stream>>>(wsp, x, W, b, out);
}

// Round 18
// 64.906 us; speedup vs baseline: 1.0106x; 1.0106x over previous
//
#include <hip/hip_runtime.h>
#include <stdint.h>

// SCLinear: out = sc_mat_mac_p(x, W, b, lut, 32)  (forward value of
// lin + stop_grad(p - lin) is exactly p).
// lut[i][j] == floor(i*j/32)  =>  sgn*lut[|a|,|b|] == trunc-toward-zero(a*b/32).
// Exact small-integer arithmetic; no lut memory needed.
//
// R31 == R29 verbatim (measured best, 64.79us). R30's issue-early/
// pipeline attempt regressed to 65.59 (VGPR pressure + front-loaded L1
// traffic); reverting per post-mortem. Session ladder: 74.7 (R13) ->
// 71.7 (R26 coalesced wave-per-row) -> 67.2 (R28 float-trick + packed
// butterfly) -> 64.8 (R29 4-rows-in-flight). Decomposition of 64.8:
// 40.6us harness fill (83% HBM peak, its own roofline) + ~10.7us
// dispatch/graph residual (R14-R13; R15 direct) + ~13.5us kernel
// (occupancy-insensitive per R26==R27, pipeline-insensitive per R30).
//
// R29: R28 + 4-ROWS-IN-FLIGHT REDUCTION (DS-pipe cut ~2.7x).
// Wave = 4 groups x 16 lanes; group g handles row 4c+g in outer
// iteration c; each lane owns a 16-element k-slice (4x float4, 8-lines/
// instr coalescing). Row-sum = 4-step within-16-lane packed butterfly
// shared by 4 rows -> 16 steps/wave + 8 x-preload ds_reads + 4 final
// gather shfls. Bounds: per-lane partial <= 512, row sum <= 8192 ->
// int16 packing safe. max|W| union over lanes covers all rows x all k.
//  * FLOAT-TRICK MAC: trunc(av*bv/32) == (int)((av/32.0f)*truncf(wf*
//    sn1f)); av/32 dyadic-exact, |av*bv|<=1024 fp32-exact, cvt truncs.
//  * coalesced loads, W read once per block.
//  * communication-free dmax (fold max|W| into row loop + |b|).
//  * publish-early/poll-late amax (sc0sc1), speculative (5,5) + exact
//    block-uniform fixup for arbitrary inputs.
// 256 blocks x 1024 threads. wsp[bx] = block bx's x-rowpair absmax
// (bit31==0 ready flag; harness poison 0xAA.. has bit31=1).

#define MROWS 512
#define KDIM  256
#define OCOLS 256
#define NTHR  1024
#define RPB   2
#define NBLK  (MROWS / RPB)     // 256
#define NWAVE (NTHR / 64)       // 16
#define ROWS_PER_WAVE (OCOLS / NWAVE)   // 16
#define E2_GUESS 5
#define E1_GUESS 5

typedef unsigned int u32x4 __attribute__((ext_vector_type(4)));

__device__ __forceinline__ void store_uc(unsigned int* p, unsigned int v) {
    asm volatile("global_store_dword %0, %1, off sc0 sc1"
                 :: "v"((unsigned long long)(uintptr_t)p), "v"(v) : "memory");
}
__device__ __forceinline__ u32x4 load_uc4(const unsigned int* p) {
    u32x4 v;
    asm volatile("global_load_dwordx4 %0, %1, off sc0 sc1\n\t"
                 "s_waitcnt vmcnt(0)"
                 : "=v"(v) : "v"((unsigned long long)(uintptr_t)p) : "memory");
    return v;
}
__device__ __forceinline__ unsigned int pk_add_i16(unsigned int a, unsigned int b) {
    unsigned int d;
    asm("v_pk_add_i16 %0, %1, %2" : "=v"(d) : "v"(a), "v"(b));
    return d;
}

__device__ __forceinline__ void get_scales(float amax, float dmax, int& e2, int& e1) {
    if (amax == 0.0f) amax = 1.0f;
    if (dmax == 0.0f) dmax = 1.0f;
    float q2 = 32.0f / amax;
    float q1 = 32.0f / dmax;
    int f2 = (q2 >= 1073741824.0f) ? 0x40000000 : (int)floorf(q2);
    int f1 = (q1 >= 1073741824.0f) ? 0x40000000 : (int)floorf(q1);
    if (f2 < 1) f2 = 1;
    if (f1 < 1) f1 = 1;
    e2 = 31 - __clz(f2);
    e1 = 31 - __clz(f1);
}

__device__ __forceinline__ float max4(float4 v) {
    return fmaxf(fmaxf(fabsf(v.x), fabsf(v.y)), fmaxf(fabsf(v.z), fabsf(v.w)));
}

// Wave-cooperative MAC, 4 rows in flight. Lane: t=lane&15 (k-slice),
// g=lane>>4 (row group). Outer iter c: group g computes row
// obase + 4*((c+rot)&3) + g over the lane's 16 k-elements; 4-step packed
// butterfly within the 16-lane group reduces all 4 rows at once.
// Returns packed {s1:hi,s0:lo} for this lane's target row obase+(lane&15).
// Folds max|W| over everything this lane loaded into wmax.
__device__ __forceinline__ unsigned int wave_mac(const float* __restrict__ W,
                                                 int obase, int lane, int rot,
                                                 u32x4 xp0, u32x4 xp1,
                                                 float sn1f, float& wmax) {
    // av/32 floats for the lane's 16 k-elements x 2 x-rows (dyadic-exact).
    float a0f[4][4], a1f[4][4];
    unsigned int xw0[4] = {xp0.x, xp0.y, xp0.z, xp0.w};
    unsigned int xw1[4] = {xp1.x, xp1.y, xp1.z, xp1.w};
    #pragma unroll
    for (int c2 = 0; c2 < 4; ++c2) {
        #pragma unroll
        for (int j = 0; j < 4; ++j) {
            a0f[c2][j] = (float)(((int)(xw0[c2] << (24 - 8 * j))) >> 24) * 0.03125f;
            a1f[c2][j] = (float)(((int)(xw1[c2] << (24 - 8 * j))) >> 24) * 0.03125f;
        }
    }
    const float4* wq = (const float4*)W;
    const int t = lane & 15;
    const int g = lane >> 4;
    unsigned int res0 = 0, res1 = 0, res2 = 0, res3 = 0;
    #pragma unroll
    for (int c = 0; c < 4; ++c) {
        const int cc = (c + rot) & 3;                 // wave-uniform
        const int o  = obase + 4 * cc + g;
        float4 wv[4];
        #pragma unroll
        for (int c2 = 0; c2 < 4; ++c2)
            wv[c2] = wq[(size_t)o * (KDIM / 4) + t + 16 * c2];
        int s0 = 0, s1 = 0;
        #pragma unroll
        for (int c2 = 0; c2 < 4; ++c2) {
            wmax = fmaxf(wmax, max4(wv[c2]));
            float wf[4] = {wv[c2].x, wv[c2].y, wv[c2].z, wv[c2].w};
            #pragma unroll
            for (int j = 0; j < 4; ++j) {
                float bvf = truncf(wf[j] * sn1f);     // == (float)bv, exact
                s0 += (int)(a0f[c2][j] * bvf);        // == trunc(av0*bv/32)
                s1 += (int)(a1f[c2][j] * bvf);
            }
        }
        // |per-lane partial| <= 512, |row sum| <= 8192 -> int16-safe.
        unsigned int s = (unsigned int)(s0 & 0xFFFF) | ((unsigned int)s1 << 16);
        #pragma unroll
        for (int sft = 8; sft >= 1; sft >>= 1)        // within-16 butterfly
            s = pk_add_i16(s, (unsigned int)__shfl_xor((int)s, sft, 64));
        if (c == 0) res0 = s; else if (c == 1) res1 = s;
        else if (c == 2) res2 = s; else res3 = s;
    }
    // Gather: lane's target row r=lane&15 was produced by group r&3 in the
    // iteration c with (c+rot)&3 == r>>2.
    const int r   = lane & 15;
    const int src = ((r & 3) << 4) + t;               // any lane of group r&3
    unsigned int v0 = (unsigned int)__shfl((int)res0, src, 64);
    unsigned int v1 = (unsigned int)__shfl((int)res1, src, 64);
    unsigned int v2 = (unsigned int)__shfl((int)res2, src, 64);
    unsigned int v3 = (unsigned int)__shfl((int)res3, src, 64);
    const int csel = ((r >> 2) - rot) & 3;
    return (csel == 0) ? v0 : (csel == 1) ? v1 : (csel == 2) ? v2 : v3;
}

__global__ __launch_bounds__(NTHR)
void k_one(unsigned int* __restrict__ wsp, const float* __restrict__ x,
           const float* __restrict__ W, const float* __restrict__ b,
           float* __restrict__ out) {
    __shared__ unsigned int a_sh[RPB][KDIM / 4];
    __shared__ float sm[2];          // x-rowpair partials from waves 0,1
    __shared__ float smd[NWAVE];     // dmax partials
    __shared__ int s_e[2];

    const int tid  = threadIdx.x;
    const int lane = tid & 63;
    const int w    = tid >> 6;
    const int bx   = blockIdx.x;
    const int m0   = bx * RPB;
    const int rot  = bx & 3;

    const float4* xf = (const float4*)x;

    // ---- speculative quantize of the block's 2 x-rows + rowpair amax ----
    float rm = 0.0f;
    if (tid < RPB * (KDIM / 4)) {            // 128 threads (waves 0,1)
        const int rr = tid >> 6;
        const int oo = tid & 63;
        float4 xv = xf[(size_t)(m0 + rr) * (KDIM / 4) + oo];
        rm = max4(xv);
        const float g2 = (float)(1 << E2_GUESS);
        int a0 = (int)(xv.x * g2) & 0xFF;
        int a1 = (int)(xv.y * g2) & 0xFF;
        int a2 = (int)(xv.z * g2) & 0xFF;
        int a3 = (int)(xv.w * g2) & 0xFF;
        a_sh[rr][oo] = (unsigned int)(a0 | (a1 << 8) | (a2 << 16) | (a3 << 24));
    }
    if (w < 2) {
        #pragma unroll
        for (int s = 32; s >= 1; s >>= 1)
            rm = fmaxf(rm, __shfl_xor(rm, s, 64));
        if (lane == 0) sm[w] = rm;
    }
    __syncthreads();
    // ---- PUBLISH EARLY: one dword per block ----
    if (tid == 0)
        store_uc(&wsp[bx], __float_as_uint(fmaxf(sm[0], sm[1])));

    // ---- x-slice preload (8 ds_reads) + coalesced 4-row-group MAC ----
    const int obase = w * ROWS_PER_WAVE;
    const int t = lane & 15;
    u32x4 xp0, xp1;
    xp0.x = a_sh[0][t];      xp0.y = a_sh[0][t + 16];
    xp0.z = a_sh[0][t + 32]; xp0.w = a_sh[0][t + 48];
    xp1.x = a_sh[1][t];      xp1.y = a_sh[1][t + 16];
    xp1.z = a_sh[1][t + 32]; xp1.w = a_sh[1][t + 48];
    float wm = 0.0f;
    unsigned int res = wave_mac(W, obase, lane, rot, xp0, xp1,
                                (float)(1 << E1_GUESS), wm);

    const float bo = b[obase + (lane & 15)];
    wm = fmaxf(wm, fabsf(bo));               // waves jointly cover all of b
    #pragma unroll
    for (int s = 32; s >= 1; s >>= 1)
        wm = fmaxf(wm, __shfl_xor(wm, s, 64));
    if (lane == 0) smd[w] = wm;
    __syncthreads();

    // ---- CONSUME LATE: poll the 256 block maxes (one dwordx4/lane) ----
    if (w == 0) {
        u32x4 u;
        bool ok;
        do {
            u = load_uc4(&wsp[4 * lane]);    // lanes 0..63 cover 256 dwords
            ok = __all(((u.x | u.y | u.z | u.w) & 0x80000000u) == 0u);
            if (!ok) __builtin_amdgcn_s_sleep(1);
        } while (!ok);
        float va = fmaxf(fmaxf(__uint_as_float(u.x), __uint_as_float(u.y)),
                         fmaxf(__uint_as_float(u.z), __uint_as_float(u.w)));
        #pragma unroll
        for (int s = 32; s >= 1; s >>= 1)
            va = fmaxf(va, __shfl_xor(va, s, 64));
        if (lane == 0) {
            float vd = smd[0];
            #pragma unroll
            for (int i = 1; i < NWAVE; ++i) vd = fmaxf(vd, smd[i]);
            int e2, e1;
            get_scales(va, vd, e2, e1);      // vd is EXACT local dmax(W,b)
            s_e[0] = e2; s_e[1] = e1;
        }
    }
    __syncthreads();

    const int e2 = s_e[0];
    const int e1 = s_e[1];

    // ---- block-uniform fixup if the guess was wrong (never for bench
    //      data; exact for arbitrary inputs) ----
    if ((e2 != E2_GUESS) | (e1 != E1_GUESS)) {
        if (tid < RPB * (KDIM / 4)) {
            const int rr = tid >> 6;
            const int oo = tid & 63;
            float4 xv = xf[(size_t)(m0 + rr) * (KDIM / 4) + oo];
            const float t2 = (float)(1 << e2);
            int a0 = (int)(xv.x * t2) & 0xFF;
            int a1 = (int)(xv.y * t2) & 0xFF;
            int a2 = (int)(xv.z * t2) & 0xFF;
            int a3 = (int)(xv.w * t2) & 0xFF;
            a_sh[rr][oo] = (unsigned int)(a0 | (a1 << 8) | (a2 << 16) | (a3 << 24));
        }
        __syncthreads();
        u32x4 yp0, yp1;
        yp0.x = a_sh[0][t];      yp0.y = a_sh[0][t + 16];
        yp0.z = a_sh[0][t + 32]; yp0.w = a_sh[0][t + 48];
        yp1.x = a_sh[1][t];      yp1.y = a_sh[1][t + 16];
        yp1.z = a_sh[1][t + 32]; yp1.w = a_sh[1][t + 48];
        float dummy = 0.0f;
        res = wave_mac(W, obase, lane, rot, yp0, yp1, (float)(1 << e1), dummy);
    }

    // ---- epilogue: lanes 0..15 store both x-rows for their column ----
    if (lane < 16) {
        const int s0 = (int)(short)(res & 0xFFFF);
        const int s1 = (int)res >> 16;
        const float sn1f = (float)(1 << e1);
        const int cc = (int)(bo * sn1f);
        const int mask = (1 << e2) - 1;
        const int d0 = ((s0 + ((s0 >> 31) & mask)) >> e2) + cc;
        const int d1 = ((s1 + ((s1 >> 31) & mask)) >> e2) + cc;
        const float inv = 1.0f / sn1f;
        out[(size_t)m0 * OCOLS + obase + lane]       = (float)d0 * inv;
        out[(size_t)(m0 + 1) * OCOLS + obase + lane] = (float)d1 * inv;
    }
}

extern "C" void kernel_launch(void* const* d_in, const int* in_sizes, int n_in,
                              void* d_out, int out_size, void* d_ws, size_t ws_size,
                              hipStream_t stream) {
    const float* x = (const float*)d_in[0];
    const float* W = (const float*)d_in[1];
    const float* b = (const float*)d_in[2];
    // d_in[3] (lut) unused: lut[i][j] == floor(i*j/32), computed in-ALU.
    float* out = (float*)d_out;
    unsigned int* wsp = (unsigned int*)d_ws;   // 1 KB: per-block x-rowpair maxes

    k_one<<<NBLK, NTHR, 0, stream>>>(wsp, x, W, b, out);
}